// Round 6
// baseline (26.651 us; speedup 1.0000x reference)
//
#include <hip/hip_runtime.h>

// y[t][o] = sum_e cos(x[t][e] + theta[e]) * w[o][e]
// tokens = 128*8192 = 1048576, E = 16.
//
// Slot layout: one float4 per lane per iteration; quarter q = tid&3 constant
// per thread; aligned 4-lane quads share a token. Coalesced 16B/lane ld/st.
// z exchanged via quad shfl_xor (DPP). Weights held in 64 VGPRs per lane,
// loaded from LDS once. y stored non-temporally (bypass L2/L3).
// Round 6: J=8, grid=2048 -> exactly 8 blocks/CU (32 waves/CU) in ONE
// residency generation, 8 KB of loads in flight per lane.

typedef float floatx4 __attribute__((ext_vector_type(4)));

constexpr int E = 16;
constexpr int BLOCK = 256;
constexpr int J = 8;                         // float4 slots per thread
constexpr long long NTOK = 128LL * 8192LL;   // 1048576
constexpr long long NSLOT = NTOK * 4;        // 4194304 float4 slots

__global__ __launch_bounds__(BLOCK) void mhaq_kernel(
    const float4* __restrict__ x4,
    const float* __restrict__ theta,
    const float* __restrict__ w,     // [o][e] row-major, 16x16
    floatx4* __restrict__ y4)
{
    __shared__ float ws[E * E];

    const int tid = threadIdx.x;
    ws[tid] = w[tid];                // BLOCK == 256 == E*E exactly
    __syncthreads();

    const int q = tid & 3;           // my quarter (element block) within token
    const float4 th = reinterpret_cast<const float4*>(theta)[q];

    const long long base = (long long)blockIdx.x * (BLOCK * J) + tid;

    // issue all x loads up-front (8 in flight per lane)
    float4 v[J];
    #pragma unroll
    for (int j = 0; j < J; ++j)
        v[j] = x4[base + (long long)j * BLOCK];

    // Hoisted weights: wq[oo][d] = W row (4q+oo), element chunk (q^d).
    float4 wq[4][4];
    #pragma unroll
    for (int oo = 0; oo < 4; ++oo) {
        #pragma unroll
        for (int d = 0; d < 4; ++d) {
            wq[oo][d] = *reinterpret_cast<const float4*>(
                &ws[(4 * q + oo) * E + ((q ^ d) * 4)]);
        }
    }

    #pragma unroll
    for (int j = 0; j < J; ++j) {
        // my 4 z values: e = 4q + k
        float zb[4][4];              // zb[d][k] = z of lane^d (quarter q^d)
        zb[0][0] = __cosf(v[j].x + th.x);
        zb[0][1] = __cosf(v[j].y + th.y);
        zb[0][2] = __cosf(v[j].z + th.z);
        zb[0][3] = __cosf(v[j].w + th.w);

        #pragma unroll
        for (int d = 1; d < 4; ++d) {
            #pragma unroll
            for (int k = 0; k < 4; ++k)
                zb[d][k] = __shfl_xor(zb[0][k], d, 4);
        }

        // my 4 outputs: o = 4q + oo; zb[d] holds element chunk (q^d)
        float acc0 = 0.f, acc1 = 0.f, acc2 = 0.f, acc3 = 0.f;
        #pragma unroll
        for (int d = 0; d < 4; ++d) {
            acc0 += zb[d][0] * wq[0][d].x + zb[d][1] * wq[0][d].y
                  + zb[d][2] * wq[0][d].z + zb[d][3] * wq[0][d].w;
            acc1 += zb[d][0] * wq[1][d].x + zb[d][1] * wq[1][d].y
                  + zb[d][2] * wq[1][d].z + zb[d][3] * wq[1][d].w;
            acc2 += zb[d][0] * wq[2][d].x + zb[d][1] * wq[2][d].y
                  + zb[d][2] * wq[2][d].z + zb[d][3] * wq[2][d].w;
            acc3 += zb[d][0] * wq[3][d].x + zb[d][1] * wq[3][d].y
                  + zb[d][2] * wq[3][d].z + zb[d][3] * wq[3][d].w;
        }

        floatx4 out;
        out.x = acc0; out.y = acc1; out.z = acc2; out.w = acc3;
        __builtin_nontemporal_store(out, &y4[base + (long long)j * BLOCK]);
    }
}

extern "C" void kernel_launch(void* const* d_in, const int* in_sizes, int n_in,
                              void* d_out, int out_size, void* d_ws, size_t ws_size,
                              hipStream_t stream) {
    const float4* x4   = (const float4*)d_in[0];
    const float* theta = (const float*)d_in[1];
    const float* w_out = (const float*)d_in[2];
    floatx4* y4 = (floatx4*)d_out;

    const int grid = (int)(NSLOT / (BLOCK * J));   // 2048, exact
    mhaq_kernel<<<grid, BLOCK, 0, stream>>>(x4, theta, w_out, y4);
}

// Round 7
// 25.602 us; speedup vs baseline: 1.0410x; 1.0410x over previous
//
#include <hip/hip_runtime.h>

// y[t][o] = sum_e cos(x[t][e] + theta[e]) * w[o][e]
// tokens = 128*8192 = 1048576, E = 16.
//
// Slot layout: one float4 per lane per iteration; quarter q = tid&3 constant
// per thread; aligned 4-lane quads share a token. Coalesced 16B/lane ld/st.
// z exchanged via quad shfl_xor (DPP). Weights loaded DIRECTLY from global
// into 64 VGPRs (4 distinct addrs/wave per load -> L1 broadcast; no LDS, no
// barrier, no prologue serialization). y stored non-temporally.
// J=4/grid=4096 is the measured-best geometry (J=8 regressed).

typedef float floatx4 __attribute__((ext_vector_type(4)));

constexpr int E = 16;
constexpr int BLOCK = 256;
constexpr int J = 4;                         // float4 slots per thread
constexpr long long NTOK = 128LL * 8192LL;   // 1048576
constexpr long long NSLOT = NTOK * 4;        // 4194304 float4 slots

__global__ __launch_bounds__(BLOCK) void mhaq_kernel(
    const float4* __restrict__ x4,
    const float4* __restrict__ theta4,
    const float4* __restrict__ w4,   // [o][e] row-major 16x16 = 64 float4 chunks
    floatx4* __restrict__ y4)
{
    const int tid = threadIdx.x;
    const int q = tid & 3;           // my quarter (element block) within token

    const long long base = (long long)blockIdx.x * (BLOCK * J) + tid;

    // issue all x loads up-front (4 in flight per lane)
    float4 v[J];
    #pragma unroll
    for (int j = 0; j < J; ++j)
        v[j] = x4[base + (long long)j * BLOCK];

    const float4 th = theta4[q];

    // Weights direct from global: wq[oo][d] = W row (4q+oo), chunk (q^d).
    // Global float4 index = row*4 + chunk.
    float4 wq[4][4];
    #pragma unroll
    for (int oo = 0; oo < 4; ++oo) {
        #pragma unroll
        for (int d = 0; d < 4; ++d) {
            wq[oo][d] = w4[(4 * q + oo) * 4 + (q ^ d)];
        }
    }

    #pragma unroll
    for (int j = 0; j < J; ++j) {
        // my 4 z values: e = 4q + k
        float zb[4][4];              // zb[d][k] = z of lane^d (quarter q^d)
        zb[0][0] = __cosf(v[j].x + th.x);
        zb[0][1] = __cosf(v[j].y + th.y);
        zb[0][2] = __cosf(v[j].z + th.z);
        zb[0][3] = __cosf(v[j].w + th.w);

        #pragma unroll
        for (int d = 1; d < 4; ++d) {
            #pragma unroll
            for (int k = 0; k < 4; ++k)
                zb[d][k] = __shfl_xor(zb[0][k], d, 4);
        }

        // my 4 outputs: o = 4q + oo; zb[d] holds element chunk (q^d)
        float acc0 = 0.f, acc1 = 0.f, acc2 = 0.f, acc3 = 0.f;
        #pragma unroll
        for (int d = 0; d < 4; ++d) {
            acc0 += zb[d][0] * wq[0][d].x + zb[d][1] * wq[0][d].y
                  + zb[d][2] * wq[0][d].z + zb[d][3] * wq[0][d].w;
            acc1 += zb[d][0] * wq[1][d].x + zb[d][1] * wq[1][d].y
                  + zb[d][2] * wq[1][d].z + zb[d][3] * wq[1][d].w;
            acc2 += zb[d][0] * wq[2][d].x + zb[d][1] * wq[2][d].y
                  + zb[d][2] * wq[2][d].z + zb[d][3] * wq[2][d].w;
            acc3 += zb[d][0] * wq[3][d].x + zb[d][1] * wq[3][d].y
                  + zb[d][2] * wq[3][d].z + zb[d][3] * wq[3][d].w;
        }

        floatx4 out;
        out.x = acc0; out.y = acc1; out.z = acc2; out.w = acc3;
        __builtin_nontemporal_store(out, &y4[base + (long long)j * BLOCK]);
    }
}

extern "C" void kernel_launch(void* const* d_in, const int* in_sizes, int n_in,
                              void* d_out, int out_size, void* d_ws, size_t ws_size,
                              hipStream_t stream) {
    const float4* x4     = (const float4*)d_in[0];
    const float4* theta4 = (const float4*)d_in[1];
    const float4* w4     = (const float4*)d_in[2];
    floatx4* y4 = (floatx4*)d_out;

    const int grid = (int)(NSLOT / (BLOCK * J));   // 4096, exact
    mhaq_kernel<<<grid, BLOCK, 0, stream>>>(x4, theta4, w4, y4);
}